// Round 14
// baseline (237.979 us; speedup 1.0000x reference)
//
#include <hip/hip_runtime.h>

#define NPOS    65536      // B*D*H*W
#define CDIM    64
#define KCODES  1024
#define NCHUNK  8          // K split factor
#define KCHUNK  128        // KCODES / NCHUNK
#define SPATIAL 16384      // D*H*W
#define QELEMS  4194304    // B*C*D*H*W

// ws layout: u64 wsu[NPOS] (packed mono_score<<10|idx, atomicMin target, init 0xFF);
//            float loss accumulator at byte offset NPOS*8 (init 0).

__global__ __launch_bounds__(256, 2) void k_search(const float* __restrict__ z_e,
                                                   const float* __restrict__ emb,
                                                   unsigned long long* __restrict__ wsu) {
    __shared__ float nrm[KCHUNK];                 // 512 B only — occupancy unaffected
    const int t     = threadIdx.x;
    const int bp    = blockIdx.x >> 3;            // position block
    const int bk    = blockIdx.x & 7;             // K chunk (block-uniform -> scalar/uniform loads)
    const int kbase = bk * KCHUNK;

    // in-block codebook norms for this chunk (emb is L2-hot; same expression as verified k_norms)
    if (t < KCHUNK) {
        const float4* e4 = (const float4*)(emb + (size_t)(kbase + t) * CDIM);
        float s = 0.0f;
#pragma unroll
        for (int c = 0; c < CDIM / 4; ++c) {
            float4 e = e4[c];
            s += e.x * e.x + e.y * e.y + e.z * e.z + e.w * e.w;
        }
        nrm[t] = s;
    }

    const int n   = bp * 256 + t;
    const int b   = n >> 14;                      // / SPATIAL
    const int dhw = n & (SPATIAL - 1);

    // This position's C=64 vector in registers (coalesced 256B per instr across lanes)
    const float* zb = z_e + (size_t)b * (CDIM * SPATIAL) + dhw;
    float x[CDIM];
#pragma unroll
    for (int c = 0; c < CDIM; ++c) x[c] = zb[(size_t)c * SPATIAL];

    __syncthreads();

    const float* __restrict__ ep = emb + (size_t)kbase * CDIM;

    unsigned long long best = ~0ull;
#pragma unroll 2
    for (int k = 0; k < KCHUNK; ++k) {
        const float4* e4 = (const float4*)(ep + (size_t)k * CDIM);
        float s0 = 0.f, s1 = 0.f, s2 = 0.f, s3 = 0.f;
#pragma unroll
        for (int c = 0; c < CDIM / 4; ++c) {
            float4 e = e4[c];
            s0 = fmaf(x[4 * c + 0], e.x, s0);
            s1 = fmaf(x[4 * c + 1], e.y, s1);
            s2 = fmaf(x[4 * c + 2], e.z, s2);
            s3 = fmaf(x[4 * c + 3], e.w, s3);
        }
        const float dot   = (s0 + s1) + (s2 + s3);
        const float score = fmaf(-2.0f, dot, nrm[k]);
        // pack: monotonic f32 bits (score-major) | global code idx (minor, 10 bits)
        unsigned u    = __float_as_uint(score);
        unsigned mono = (u & 0x80000000u) ? ~u : (u | 0x80000000u);
        unsigned long long pk = ((unsigned long long)mono << 10) | (unsigned)(kbase + k);
        if (pk < best) best = pk;                 // strict < keeps first occurrence
    }

    // one device atomic per thread; min over chunks == global argmin w/ numpy tie-break
    atomicMin(&wsu[n], best);
}

__global__ void k_finalize(const float* __restrict__ z_e,
                           const float* __restrict__ emb,
                           float* __restrict__ out,
                           const unsigned long long* __restrict__ wsu,
                           float* __restrict__ lossf) {
    const int n    = blockIdx.x * 256 + threadIdx.x;
    const int b    = n >> 14;
    const int dhw  = n & (SPATIAL - 1);
    const int bidx = (int)(wsu[n] & 1023ull);

    out[QELEMS + 2 + n] = (float)bidx;            // indices output (f32 buffer)

    const float*  zb = z_e + (size_t)b * (CDIM * SPATIAL) + dhw;
    float*        qb = out + (size_t)b * (CDIM * SPATIAL) + dhw;
    const float4* e4 = (const float4*)(emb + (size_t)bidx * CDIM);

    float lsum = 0.0f;
#pragma unroll
    for (int c4 = 0; c4 < CDIM / 4; ++c4) {
        float4 ev = e4[c4];
        float  evs[4] = {ev.x, ev.y, ev.z, ev.w};
#pragma unroll
        for (int j = 0; j < 4; ++j) {
            int   c  = 4 * c4 + j;
            float xv = zb[(size_t)c * SPATIAL];
            float d  = evs[j] - xv;               // quantized - z_e (f32 rounding)
            qb[(size_t)c * SPATIAL] = xv + d;     // straight-through arithmetic
            lsum = fmaf(d, d, lsum);
        }
    }
#pragma unroll
    for (int off = 32; off > 0; off >>= 1) lsum += __shfl_down(lsum, off, 64);
    if ((threadIdx.x & 63) == 0) atomicAdd(lossf, lsum);
}

__global__ void k_loss(const float* __restrict__ lossf, float* __restrict__ out) {
    const float m = lossf[0] / (float)QELEMS;
    out[QELEMS]     = m;  // codebook_loss
    out[QELEMS + 1] = m;  // commitment_loss (same forward value)
}

extern "C" void kernel_launch(void* const* d_in, const int* in_sizes, int n_in,
                              void* d_out, int out_size, void* d_ws, size_t ws_size,
                              hipStream_t stream) {
    const float* z_e = (const float*)d_in[0];
    const float* emb = (const float*)d_in[1];
    float*       out = (float*)d_out;
    unsigned long long* wsu = (unsigned long long*)d_ws;
    float*       lossf = (float*)((char*)d_ws + (size_t)NPOS * 8);

    hipMemsetAsync(d_ws, 0xFF, (size_t)NPOS * 8, stream);      // packed slots = +inf
    hipMemsetAsync((void*)lossf, 0, 4, stream);                // loss accumulator = 0

    k_search<<<(NPOS / 256) * NCHUNK, 256, 0, stream>>>(z_e, emb, wsu);
    k_finalize<<<NPOS / 256, 256, 0, stream>>>(z_e, emb, out, wsu, lossf);
    k_loss<<<1, 1, 0, stream>>>(lossf, out);
}